// Round 2
// baseline (1064.932 us; speedup 1.0000x reference)
//
#include <hip/hip_runtime.h>

#define BSZ 256
#define SEQ 2048
#define NT  64
#define KS  5.0f

static __device__ __forceinline__ float wave_red_max(float x) {
#pragma unroll
    for (int d = 1; d < 64; d <<= 1) x = fmaxf(x, __shfl_xor(x, d));
    return x;
}
static __device__ __forceinline__ float wave_red_sum(float x) {
#pragma unroll
    for (int d = 1; d < 64; d <<= 1) x += __shfl_xor(x, d);
    return x;
}

// ---------------------------------------------------------------------------
// Forward algorithm in exp-domain, one batch per 64-thread (1-wave) block.
// Lane j owns tag j. b[j] = exp(alpha[j] - C), C wave-uniform log-scale.
// Emissions pre-shifted by KS (C += KS per unmasked step) so |log-drift| is
// small; renorm every 8 steps computed LAZILY off the critical chain.
// No __syncthreads: single wave, LDS ops are in-order per wave; wave_barrier
// is a compile-time ordering fence only (keeps vmcnt prefetch alive).
// ---------------------------------------------------------------------------
__global__ __launch_bounds__(64) void crf_forward_kernel(
    const float* __restrict__ logits,
    const int*   __restrict__ tags,
    const int*   __restrict__ mask,
    const float* __restrict__ trans,
    const float* __restrict__ startT,
    const float* __restrict__ endT,
    float* __restrict__ den_out,
    float* __restrict__ numemit_out)
{
    const int b = blockIdx.x;
    const int j = threadIdx.x;
    const float* __restrict__ L  = logits + (size_t)b * SEQ * NT;
    const int*   __restrict__ tg = tags + (size_t)b * SEQ;
    const int*   __restrict__ mk = mask + (size_t)b * SEQ;

    __shared__ __align__(16) float sb[2][NT];

    // E column j: E[i][j] = exp(trans[i][j])
    float Ecol[NT];
#pragma unroll
    for (int i = 0; i < NT; ++i) Ecol[i] = __expf(trans[i * NT + j]);

    // ---- t = 0 ----
    float em0  = L[j];
    int   m0   = mk[0];
    int   tag0 = tg[0] * m0;
    float alpha0 = startT[j] + em0;
    float C  = wave_red_max(alpha0);
    float bj = __expf(alpha0 - C);
    float numacc = (m0 && j == tag0) ? em0 : 0.0f;

    // one step of the recurrence; buf is a compile-time literal
    auto STEP = [&](int t, int buf, float em, float F, int mt, int tagt) {
        sb[buf][j] = bj;
        __builtin_amdgcn_wave_barrier();
        const float4* __restrict__ p = (const float4*)sb[buf];
        float a0 = 0.f, a1 = 0.f, a2 = 0.f, a3 = 0.f;
#pragma unroll
        for (int i4 = 0; i4 < NT / 4; ++i4) {
            float4 v = p[i4];
            a0 = fmaf(v.x, Ecol[4 * i4 + 0], a0);
            a1 = fmaf(v.y, Ecol[4 * i4 + 1], a1);
            a2 = fmaf(v.z, Ecol[4 * i4 + 2], a2);
            a3 = fmaf(v.w, Ecol[4 * i4 + 3], a3);
        }
        float s    = (a0 + a1) + (a2 + a3);
        float bnew = s * F;
        if (mt) { bj = bnew; C += KS; }   // mask: wave-uniform select
        numacc += (mt && j == tagt && t < SEQ - 1) ? em : 0.0f;
    };

    // ---- prefetch block t0 = 8 ----
    float emN[8];
    {
        const float* Lp = L + 8 * NT + j;
#pragma unroll
        for (int u = 0; u < 8; ++u) emN[u] = Lp[u * NT];
    }
    int4 mN0 = *(const int4*)(mk + 8);
    int4 mN1 = *(const int4*)(mk + 12);
    int4 tN0 = *(const int4*)(tg + 8);
    int4 tN1 = *(const int4*)(tg + 12);

    // ---- peel t = 1..7 (latency exposed once; negligible) ----
#pragma unroll
    for (int t = 1; t < 8; ++t) {
        float em = L[t * NT + j];
        float F  = __expf(em - KS);
        int   mt = mk[t];
        int   tagt = tg[t] * mt;
        STEP(t, t & 1, em, F, mt, tagt);
    }
    float rnv = bj;   // renorm snapshot

    // ---- main loop: 255 blocks of 8 steps, t = 8..2047 ----
    for (int t0 = 8; t0 < SEQ; t0 += 8) {
        // unpack current block's prefetched data
        float e0 = emN[0], e1 = emN[1], e2 = emN[2], e3 = emN[3];
        float e4 = emN[4], e5 = emN[5], e6 = emN[6], e7 = emN[7];
        int mt0 = mN0.x, mt1 = mN0.y, mt2 = mN0.z, mt3 = mN0.w;
        int mt4 = mN1.x, mt5 = mN1.y, mt6 = mN1.z, mt7 = mN1.w;
        int tg0_ = tN0.x * mt0, tg1_ = tN0.y * mt1, tg2_ = tN0.z * mt2, tg3_ = tN0.w * mt3;
        int tg4_ = tN1.x * mt4, tg5_ = tN1.y * mt5, tg6_ = tN1.z * mt6, tg7_ = tN1.w * mt7;

        // issue prefetch for next block (clamped; redundant loads on last iter)
        int tn = t0 + 8;
        if (tn > SEQ - 8) tn = SEQ - 8;
        {
            const float* Lq = L + tn * NT + j;
#pragma unroll
            for (int u = 0; u < 8; ++u) emN[u] = Lq[u * NT];
        }
        mN0 = *(const int4*)(mk + tn);
        mN1 = *(const int4*)(mk + tn + 4);
        tN0 = *(const int4*)(tg + tn);
        tN1 = *(const int4*)(tg + tn + 4);

        // lazy renorm: reduce runs concurrently with STEPs below
        float mx = wave_red_max(rnv);

        float F0 = __expf(e0 - KS), F1 = __expf(e1 - KS);
        float F2 = __expf(e2 - KS), F3 = __expf(e3 - KS);
        float F4 = __expf(e4 - KS), F5 = __expf(e5 - KS);
        float F6 = __expf(e6 - KS), F7 = __expf(e7 - KS);

        STEP(t0 + 0, 0, e0, F0, mt0, tg0_);
        STEP(t0 + 1, 1, e1, F1, mt1, tg1_);
        // apply renorm (exact: uniform rescale, C compensated)
        bj = bj / mx;
        C += __logf(mx);
        STEP(t0 + 2, 0, e2, F2, mt2, tg2_);
        STEP(t0 + 3, 1, e3, F3, mt3, tg3_);
        STEP(t0 + 4, 0, e4, F4, mt4, tg4_);
        STEP(t0 + 5, 1, e5, F5, mt5, tg5_);
        STEP(t0 + 6, 0, e6, F6, mt6, tg6_);
        STEP(t0 + 7, 1, e7, F7, mt7, tg7_);
        rnv = bj;
    }

    // ---- finalize ----
    float v = bj * __expf(endT[j]);
    v      = wave_red_sum(v);
    numacc = wave_red_sum(numacc);
    if (j == 0) {
        den_out[b]     = C + __logf(v);
        numemit_out[b] = numacc;
    }
}

// ---------------------------------------------------------------------------
// Numerator transition/start/end terms + last emission term.
// ---------------------------------------------------------------------------
__global__ __launch_bounds__(256) void crf_numer_kernel(
    const float* __restrict__ logits,
    const int*   __restrict__ tags,
    const int*   __restrict__ mask,
    const float* __restrict__ trans,
    const float* __restrict__ startT,
    const float* __restrict__ endT,
    float* __restrict__ numtrans_out)
{
    const int b   = blockIdx.x;
    const int tid = threadIdx.x;

    __shared__ float st[NT * NT];
    __shared__ float redf[256];
    __shared__ int   redi[256];

    for (int i = tid; i < NT * NT; i += 256) st[i] = trans[i];
    __syncthreads();

    const int* __restrict__ tg = tags + (size_t)b * SEQ;
    const int* __restrict__ mk = mask + (size_t)b * SEQ;

    float acc = 0.0f;
    int   cnt = 0;
    for (int t = tid; t < SEQ; t += 256) {
        int mt = mk[t];
        cnt += mt;
        if (t < SEQ - 1) {
            int m1 = mk[t + 1];
            int a  = tg[t]     * mt;
            int c  = tg[t + 1] * m1;
            acc += st[a * NT + c] * (float)m1;
        }
    }
    redf[tid] = acc;
    redi[tid] = cnt;
    __syncthreads();
    for (int off = 128; off > 0; off >>= 1) {
        if (tid < off) {
            redf[tid] += redf[tid + off];
            redi[tid] += redi[tid + off];
        }
        __syncthreads();
    }

    if (tid == 0) {
        int   last_idx = redi[0] - 1;
        int   m_last   = mk[SEQ - 1];
        int   tag0     = tg[0] * mk[0];
        int   last_tag = tg[last_idx] * mk[last_idx];
        float r = redf[0] + startT[tag0] + endT[last_tag];
        r += logits[((size_t)b * SEQ + (SEQ - 1)) * NT + last_tag] * (float)m_last;
        numtrans_out[b] = r;
    }
}

// ---------------------------------------------------------------------------
// Final scalar reduction: out = sum_b (numerator - denominator).
// ---------------------------------------------------------------------------
__global__ __launch_bounds__(256) void crf_reduce_kernel(
    const float* __restrict__ den,
    const float* __restrict__ numemit,
    const float* __restrict__ numtrans,
    float* __restrict__ out)
{
    __shared__ float red[256];
    const int tid = threadIdx.x;
    red[tid] = numemit[tid] + numtrans[tid] - den[tid];
    __syncthreads();
    for (int off = 128; off > 0; off >>= 1) {
        if (tid < off) red[tid] += red[tid + off];
        __syncthreads();
    }
    if (tid == 0) out[0] = red[0];
}

// ---------------------------------------------------------------------------
extern "C" void kernel_launch(void* const* d_in, const int* in_sizes, int n_in,
                              void* d_out, int out_size, void* d_ws, size_t ws_size,
                              hipStream_t stream)
{
    const float* logits = (const float*)d_in[0];
    const int*   tags   = (const int*)  d_in[1];
    const int*   mask   = (const int*)  d_in[2];
    const float* trans  = (const float*)d_in[3];
    const float* startT = (const float*)d_in[4];
    const float* endT   = (const float*)d_in[5];
    float* out = (float*)d_out;

    float* den      = (float*)d_ws;
    float* numemit  = den + BSZ;
    float* numtrans = den + 2 * BSZ;

    crf_forward_kernel<<<BSZ, 64, 0, stream>>>(logits, tags, mask, trans,
                                               startT, endT, den, numemit);
    crf_numer_kernel<<<BSZ, 256, 0, stream>>>(logits, tags, mask, trans,
                                              startT, endT, numtrans);
    crf_reduce_kernel<<<1, 256, 0, stream>>>(den, numemit, numtrans, out);
}

// Round 4
// 462.107 us; speedup vs baseline: 2.3045x; 2.3045x over previous
//
#include <hip/hip_runtime.h>

#define BSZ 256
#define SEQ 2048
#define NT  64
#define KS  5.0f

typedef __fp16 half2_t __attribute__((ext_vector_type(2)));

static __device__ __forceinline__ float wave_red_max(float x) {
#pragma unroll
    for (int d = 1; d < 64; d <<= 1) x = fmaxf(x, __shfl_xor(x, d));
    return x;
}
static __device__ __forceinline__ float wave_red_sum(float x) {
#pragma unroll
    for (int d = 1; d < 64; d <<= 1) x += __shfl_xor(x, d);
    return x;
}

static __device__ __forceinline__ float rl_f(float v, int lane) {
    return __builtin_bit_cast(float,
        __builtin_amdgcn_readlane(__builtin_bit_cast(int, v), lane));
}
static __device__ __forceinline__ half2_t rl_h2(half2_t v, int lane) {
    return __builtin_bit_cast(half2_t,
        __builtin_amdgcn_readlane(__builtin_bit_cast(int, v), lane));
}

#if defined(__has_builtin)
#if __has_builtin(__builtin_amdgcn_fdot2) && __has_builtin(__builtin_amdgcn_cvt_pkrtz)
#define USE_DOT2 1
#endif
#endif
#ifndef USE_DOT2
#define USE_DOT2 0
#endif

// ---------------------------------------------------------------------------
// Forward algorithm in exp-domain, one batch per 64-thread (1-wave) block.
// Lane j owns tag j. b[j] = exp(alpha[j] - C), C wave-uniform log-scale.
// Matvec step uses v_readlane broadcast (SGPR operand) + v_dot2_f32_f16:
// no LDS round-trip, no barrier, E table is 32 VGPRs of f16 pairs.
// Emissions pre-shifted by KS (C += KS per unmasked step); lazy renorm /8.
// ---------------------------------------------------------------------------
__global__ __launch_bounds__(64) void crf_forward_kernel(
    const float* __restrict__ logits,
    const int*   __restrict__ tags,
    const int*   __restrict__ mask,
    const float* __restrict__ trans,
    const float* __restrict__ startT,
    const float* __restrict__ endT,
    float* __restrict__ den_out,
    float* __restrict__ numemit_out)
{
    const int b = blockIdx.x;
    const int j = threadIdx.x;
    const float* __restrict__ L  = logits + (size_t)b * SEQ * NT;
    const int*   __restrict__ tg = tags + (size_t)b * SEQ;
    const int*   __restrict__ mk = mask + (size_t)b * SEQ;

#if USE_DOT2
    // E pairs: Epair[i] = (exp(trans[2i][j]), exp(trans[2i+1][j])) as f16x2
    half2_t Epair[NT / 2];
#pragma unroll
    for (int i = 0; i < NT / 2; ++i) {
        float e0 = __expf(trans[(2 * i + 0) * NT + j]);
        float e1 = __expf(trans[(2 * i + 1) * NT + j]);
        Epair[i] = __builtin_amdgcn_cvt_pkrtz(e0, e1);
    }
#else
    float Ecol[NT];
#pragma unroll
    for (int i = 0; i < NT; ++i) Ecol[i] = __expf(trans[i * NT + j]);
#endif

    // ---- t = 0 ----
    float em0  = L[j];
    int   m0   = mk[0];
    int   tag0 = tg[0] * m0;
    float alpha0 = startT[j] + em0;
    float C  = wave_red_max(alpha0);
    float bj = __expf(alpha0 - C);
    float numacc = (m0 && j == tag0) ? em0 : 0.0f;

    auto STEP = [&](int t, float em, float F, int mt, int tagt) {
#if USE_DOT2
        // pair own value with xor-1 neighbor: even lane 2i holds (b[2i],b[2i+1])
        float nb = __shfl_xor(bj, 1);
        half2_t hp = __builtin_amdgcn_cvt_pkrtz(bj, nb);
        float a0 = 0.f, a1 = 0.f, a2 = 0.f, a3 = 0.f;
#pragma unroll
        for (int i = 0; i < NT / 2; i += 4) {
            a0 = __builtin_amdgcn_fdot2(rl_h2(hp, 2 * (i + 0)), Epair[i + 0], a0, false);
            a1 = __builtin_amdgcn_fdot2(rl_h2(hp, 2 * (i + 1)), Epair[i + 1], a1, false);
            a2 = __builtin_amdgcn_fdot2(rl_h2(hp, 2 * (i + 2)), Epair[i + 2], a2, false);
            a3 = __builtin_amdgcn_fdot2(rl_h2(hp, 2 * (i + 3)), Epair[i + 3], a3, false);
        }
#else
        float a0 = 0.f, a1 = 0.f, a2 = 0.f, a3 = 0.f;
#pragma unroll
        for (int i = 0; i < NT; i += 4) {
            a0 = fmaf(rl_f(bj, i + 0), Ecol[i + 0], a0);
            a1 = fmaf(rl_f(bj, i + 1), Ecol[i + 1], a1);
            a2 = fmaf(rl_f(bj, i + 2), Ecol[i + 2], a2);
            a3 = fmaf(rl_f(bj, i + 3), Ecol[i + 3], a3);
        }
#endif
        float s    = (a0 + a1) + (a2 + a3);
        float bnew = s * F;
        bj = mt ? bnew : bj;
        C  = mt ? C + KS : C;
        numacc += (mt && j == tagt && t < SEQ - 1) ? em : 0.0f;
    };

    // ---- prefetch block t0 = 8 ----
    float emN[8];
    {
        const float* Lp = L + 8 * NT + j;
#pragma unroll
        for (int u = 0; u < 8; ++u) emN[u] = Lp[u * NT];
    }
    int4 mN0 = *(const int4*)(mk + 8);
    int4 mN1 = *(const int4*)(mk + 12);
    int4 tN0 = *(const int4*)(tg + 8);
    int4 tN1 = *(const int4*)(tg + 12);

    // ---- peel t = 1..7 ----
#pragma unroll
    for (int t = 1; t < 8; ++t) {
        float em = L[t * NT + j];
        float F  = __expf(em - KS);
        int   mt = mk[t];
        int   tagt = tg[t] * mt;
        STEP(t, em, F, mt, tagt);
    }
    float rnv = bj;   // renorm snapshot

    // ---- main loop: blocks of 8 steps, t = 8..2047 ----
    for (int t0 = 8; t0 < SEQ; t0 += 8) {
        float e0 = emN[0], e1 = emN[1], e2 = emN[2], e3 = emN[3];
        float e4 = emN[4], e5 = emN[5], e6 = emN[6], e7 = emN[7];
        int mt0 = mN0.x, mt1 = mN0.y, mt2 = mN0.z, mt3 = mN0.w;
        int mt4 = mN1.x, mt5 = mN1.y, mt6 = mN1.z, mt7 = mN1.w;
        int tg0_ = tN0.x * mt0, tg1_ = tN0.y * mt1, tg2_ = tN0.z * mt2, tg3_ = tN0.w * mt3;
        int tg4_ = tN1.x * mt4, tg5_ = tN1.y * mt5, tg6_ = tN1.z * mt6, tg7_ = tN1.w * mt7;

        int tn = t0 + 8;
        if (tn > SEQ - 8) tn = SEQ - 8;
        {
            const float* Lq = L + tn * NT + j;
#pragma unroll
            for (int u = 0; u < 8; ++u) emN[u] = Lq[u * NT];
        }
        mN0 = *(const int4*)(mk + tn);
        mN1 = *(const int4*)(mk + tn + 4);
        tN0 = *(const int4*)(tg + tn);
        tN1 = *(const int4*)(tg + tn + 4);

        // lazy renorm reduce (off the b-chain; applied after 2 steps)
        float mx = wave_red_max(rnv);

        float F0 = __expf(e0 - KS), F1 = __expf(e1 - KS);
        float F2 = __expf(e2 - KS), F3 = __expf(e3 - KS);
        float F4 = __expf(e4 - KS), F5 = __expf(e5 - KS);
        float F6 = __expf(e6 - KS), F7 = __expf(e7 - KS);

        STEP(t0 + 0, e0, F0, mt0, tg0_);
        STEP(t0 + 1, e1, F1, mt1, tg1_);
        bj = bj / mx;          // exact uniform rescale
        C += __logf(mx);
        STEP(t0 + 2, e2, F2, mt2, tg2_);
        STEP(t0 + 3, e3, F3, mt3, tg3_);
        STEP(t0 + 4, e4, F4, mt4, tg4_);
        STEP(t0 + 5, e5, F5, mt5, tg5_);
        STEP(t0 + 6, e6, F6, mt6, tg6_);
        STEP(t0 + 7, e7, F7, mt7, tg7_);
        rnv = bj;
    }

    // ---- finalize ----
    float v = bj * __expf(endT[j]);
    v      = wave_red_sum(v);
    numacc = wave_red_sum(numacc);
    if (j == 0) {
        den_out[b]     = C + __logf(v);
        numemit_out[b] = numacc;
    }
}

// ---------------------------------------------------------------------------
// Numerator transition/start/end terms + last emission term.
// ---------------------------------------------------------------------------
__global__ __launch_bounds__(256) void crf_numer_kernel(
    const float* __restrict__ logits,
    const int*   __restrict__ tags,
    const int*   __restrict__ mask,
    const float* __restrict__ trans,
    const float* __restrict__ startT,
    const float* __restrict__ endT,
    float* __restrict__ numtrans_out)
{
    const int b   = blockIdx.x;
    const int tid = threadIdx.x;

    __shared__ float st[NT * NT];
    __shared__ float redf[256];
    __shared__ int   redi[256];

    for (int i = tid; i < NT * NT; i += 256) st[i] = trans[i];
    __syncthreads();

    const int* __restrict__ tg = tags + (size_t)b * SEQ;
    const int* __restrict__ mk = mask + (size_t)b * SEQ;

    float acc = 0.0f;
    int   cnt = 0;
    for (int t = tid; t < SEQ; t += 256) {
        int mt = mk[t];
        cnt += mt;
        if (t < SEQ - 1) {
            int m1 = mk[t + 1];
            int a  = tg[t]     * mt;
            int c  = tg[t + 1] * m1;
            acc += st[a * NT + c] * (float)m1;
        }
    }
    redf[tid] = acc;
    redi[tid] = cnt;
    __syncthreads();
    for (int off = 128; off > 0; off >>= 1) {
        if (tid < off) {
            redf[tid] += redf[tid + off];
            redi[tid] += redi[tid + off];
        }
        __syncthreads();
    }

    if (tid == 0) {
        int   last_idx = redi[0] - 1;
        int   m_last   = mk[SEQ - 1];
        int   tag0     = tg[0] * mk[0];
        int   last_tag = tg[last_idx] * mk[last_idx];
        float r = redf[0] + startT[tag0] + endT[last_tag];
        r += logits[((size_t)b * SEQ + (SEQ - 1)) * NT + last_tag] * (float)m_last;
        numtrans_out[b] = r;
    }
}

// ---------------------------------------------------------------------------
// Final scalar reduction: out = sum_b (numerator - denominator).
// ---------------------------------------------------------------------------
__global__ __launch_bounds__(256) void crf_reduce_kernel(
    const float* __restrict__ den,
    const float* __restrict__ numemit,
    const float* __restrict__ numtrans,
    float* __restrict__ out)
{
    __shared__ float red[256];
    const int tid = threadIdx.x;
    red[tid] = numemit[tid] + numtrans[tid] - den[tid];
    __syncthreads();
    for (int off = 128; off > 0; off >>= 1) {
        if (tid < off) red[tid] += red[tid + off];
        __syncthreads();
    }
    if (tid == 0) out[0] = red[0];
}

// ---------------------------------------------------------------------------
extern "C" void kernel_launch(void* const* d_in, const int* in_sizes, int n_in,
                              void* d_out, int out_size, void* d_ws, size_t ws_size,
                              hipStream_t stream)
{
    const float* logits = (const float*)d_in[0];
    const int*   tags   = (const int*)  d_in[1];
    const int*   mask   = (const int*)  d_in[2];
    const float* trans  = (const float*)d_in[3];
    const float* startT = (const float*)d_in[4];
    const float* endT   = (const float*)d_in[5];
    float* out = (float*)d_out;

    float* den      = (float*)d_ws;
    float* numemit  = den + BSZ;
    float* numtrans = den + 2 * BSZ;

    crf_forward_kernel<<<BSZ, 64, 0, stream>>>(logits, tags, mask, trans,
                                               startT, endT, den, numemit);
    crf_numer_kernel<<<BSZ, 256, 0, stream>>>(logits, tags, mask, trans,
                                              startT, endT, numtrans);
    crf_reduce_kernel<<<1, 256, 0, stream>>>(den, numemit, numtrans, out);
}